// Round 6
// baseline (181.451 us; speedup 1.0000x reference)
//
#include <hip/hip_runtime.h>
#include <hip/hip_bf16.h>
#include <cstdint>
#include <cstddef>

#define BB 256
#define RR 512
#define AA 196
#define VV 10000
#define MATT (BB*AA)   // 50176
#define NT8 8          // 8*16 = 128 cols per half (Wa2a padded to 256)

typedef float f32x4 __attribute__((ext_vector_type(4)));
typedef __bf16 bf16x8 __attribute__((ext_vector_type(8)));
typedef __bf16 bf16x4 __attribute__((ext_vector_type(4)));

#define MFMA16(a,b,c) __builtin_amdgcn_mfma_f32_16x16x32_bf16(a,b,c,0,0,0)

__device__ __forceinline__ float fast_tanh(float x){
  float ax = fabsf(x);
  float e = __expf(-2.0f*ax);
  float t = __fdividef(1.0f - e, 1.0f + e);
  return x < 0.0f ? -t : t;
}

// async global -> LDS, 16B per lane (LDS dest must be wave-uniform; HW adds lane*16)
__device__ __forceinline__ void gload16(const void* gsrc, void* ldsdst){
  __builtin_amdgcn_global_load_lds(
      (const __attribute__((address_space(1))) unsigned int*)gsrc,
      (__attribute__((address_space(3))) unsigned int*)ldsdst,
      16, 0, 0);
}

#define ABAR   asm volatile("s_barrier" ::: "memory")
#define WVM(N) asm volatile("s_waitcnt vmcnt(" #N ")" ::: "memory")

// ---------- weight/input prep ----------
// f32 -> bf16 vectorized, n4 = n/4
__global__ void cvt4_k(const float* __restrict__ src, __bf16* __restrict__ dst, int n4){
  int i = blockIdx.x*256 + threadIdx.x;
  if (i < n4){
    float4 v = ((const float4*)src)[i];
    bf16x4 o;
    o[0]=(__bf16)v.x; o[1]=(__bf16)v.y; o[2]=(__bf16)v.z; o[3]=(__bf16)v.w;
    ((bf16x4*)dst)[i] = o;
  }
}

// [total][512] bf16, rows >= nvalid zeroed. grid covers total*512.
__global__ void cvt_padrows_k(const float* __restrict__ src, __bf16* __restrict__ dst, int nvalid){
  int i = blockIdx.x*256 + threadIdx.x;
  int row = i >> 9;
  dst[i] = (__bf16)((row < nvalid) ? src[(size_t)row*512 + (i & 511)] : 0.0f);
}

__global__ void wcat2_k(const float* __restrict__ Wi2h, const float* __restrict__ Wh2h,
                        const float* __restrict__ Wr2a, __bf16* __restrict__ Wcat){
  int k = blockIdx.x*256 + threadIdx.x;   // 0..1535
  int n = blockIdx.y;                     // 0..2047
  float v;
  if (k < 512)       v = Wi2h[n*512 + k];
  else if (k < 1024) v = Wh2h[n*512 + (k-512)];
  else               v = Wr2a[n*512 + (k-1024)];
  Wcat[(size_t)n*1536 + k] = (__bf16)v;
}

__global__ void build_small_k(const float* __restrict__ ba2a, const float* __restrict__ wd2d,
                              const float* __restrict__ bi2h, const float* __restrict__ bh2h,
                              const float* __restrict__ br2a,
                              float* __restrict__ ba_pad, float* __restrict__ wd_pad,
                              float* __restrict__ bcat){
  int i = blockIdx.x*256 + threadIdx.x;
  if (i < 2048){
    bcat[i] = bi2h[i] + bh2h[i] + br2a[i];
  } else if (i < 2048+256){
    int j = i - 2048; ba_pad[j] = (j < AA) ? ba2a[j] : 0.0f;
  } else if (i < 2048+512){
    int j = i - 2304; wd_pad[j] = (j < AA) ? wd2d[j] : 0.0f;
  }
}

// ---------- pipelined bf16 GEMM: C[m][n] = sum_k A[m][k]*W[n][k] + bias[n] ----------
// BM=32, BN=64, K-chunk=64, 4 waves, 3-buffer LDS, counted vmcnt.
__global__ __launch_bounds__(256,4) void gemm3_k(
    const __bf16* __restrict__ A, const __bf16* __restrict__ Bw,
    const float* __restrict__ bias, float* __restrict__ C,
    int N, int K, int NC)
{
  __shared__ __bf16 AshAll[3*2048];   // 3 x 32x64
  __shared__ __bf16 BshAll[3*4096];   // 3 x 64x64
  const int t = threadIdx.x;
  const int l = t & 63;
  const int w = t >> 6;
  const int l15 = l & 15;
  const int g  = l >> 4;
  const int rho = l15 & 7;
  const int mrow = blockIdx.y*32;
  const int ncb  = blockIdx.x*64;

  const int arow = t >> 3, aj = t & 7;
  const __bf16* as_ = A + (size_t)(mrow + arow)*K + ((aj ^ (arow&7)) << 3);
  const int aoff = w*512;
  const __bf16* bs0_ = Bw + (size_t)(ncb + arow)*K      + ((aj ^ (arow&7)) << 3);
  const __bf16* bs1_ = Bw + (size_t)(ncb + 32 + arow)*K + ((aj ^ (arow&7)) << 3);
  const int boff0 = w*512;
  const int boff1 = 2048 + w*512;

#define G3_STAGE(B, CH) do { \
    gload16(as_  + (CH)*64, AshAll + (B)*2048 + aoff); \
    gload16(bs0_ + (CH)*64, BshAll + (B)*4096 + boff0); \
    gload16(bs1_ + (CH)*64, BshAll + (B)*4096 + boff1); \
  } while(0)

  f32x4 acc0 = {}, acc1 = {};

#define G3_COMPUTE(B) do { \
    const __bf16* As_ = AshAll + (B)*2048; \
    const __bf16* Bs_ = BshAll + (B)*4096; \
    _Pragma("unroll") \
    for (int s_ = 0; s_ < 2; s_++){ \
      int q_ = (((s_<<2)+g) ^ rho) << 3; \
      bf16x8 a0_ = *(const bf16x8*)(As_ + l15*64 + q_); \
      bf16x8 a1_ = *(const bf16x8*)(As_ + (l15+16)*64 + q_); \
      bf16x8 b_  = *(const bf16x8*)(Bs_ + (w*16+l15)*64 + q_); \
      acc0 = MFMA16(a0_, b_, acc0); \
      acc1 = MFMA16(a1_, b_, acc1); \
    } \
  } while(0)

  G3_STAGE(0,0); G3_STAGE(1,1); G3_STAGE(2,2);
  WVM(6); ABAR;
  int buf = 0;
  for (int c = 0; c < NC; c++){
    G3_COMPUTE(buf);
    if (c + 3 < NC){
      ABAR;
      G3_STAGE(buf, c+3);
      WVM(6); ABAR;
    } else if (c == NC-3){
      WVM(3); ABAR;
    } else if (c == NC-2){
      WVM(0); ABAR;
    }
    buf = (buf == 2) ? 0 : buf + 1;
  }

  int col = ncb + w*16 + l15;
  if (col < N){
    float bv = bias[col];
    #pragma unroll
    for (int r = 0; r < 4; r++){
      C[(size_t)(mrow + g*4 + r)*N + col]      = acc0[r] + bv;
      C[(size_t)(mrow + 16 + g*4 + r)*N + col] = acc1[r] + bv;
    }
  }
#undef G3_STAGE
#undef G3_COMPUTE
}

// ---------- fused attention score v6: col-split, bf16 A, high-occupancy pipeline ----------
// Block: 128 att rows x 128 cols (half of padded 256), K-chunk=32, 16 chunks.
// A and B both global_load_lds staged, 3 buffers (48KB -> 3 blocks/CU), uniform
// 4 VMEM/wave/chunk, depth-2 counted vmcnt. Partial scores -> sp[half][layer][row].
__global__ __launch_bounds__(256,3) void att_score6_k(
    const __bf16* __restrict__ att_bf, const __bf16* __restrict__ Wa2a_p,
    const float* __restrict__ ba_pad, const float* __restrict__ wd_pad,
    const float* __restrict__ att_h, float* __restrict__ sp)
{
  __shared__ __bf16 Ash[3*4096];   // 3 x [128][32]
  __shared__ __bf16 Bsh[3*4096];   // 3 x [128][32]
  const int t = threadIdx.x;
  const int l = t & 63;
  const int w = t >> 6;
  const int l15 = l & 15;
  const int g  = l >> 4;
  const int rowbase = blockIdx.x * 128;
  const int half = blockIdx.y;

  // staging: tile [128][32] bf16 = 512 slots of 16B; slot s -> row=s>>2, j=s&3,
  // source k-slot pre-swizzled jj = j ^ ((row>>1)&3)  (read side applies same XOR)
  const __bf16* asrc[2]; const __bf16* bsrc[2]; int slotb[2];
  #pragma unroll
  for (int i = 0; i < 2; i++){
    int id = i*4 + w;
    int slot = id*64 + l;
    int row = slot >> 2, j = slot & 3;
    int jj = j ^ ((row>>1)&3);
    slotb[i] = id*512;  // wave-uniform elem offset
    asrc[i] = att_bf + (size_t)(rowbase + row)*RR + (jj<<3);
    bsrc[i] = Wa2a_p + (size_t)(half*128 + row)*RR + (jj<<3);
  }

  f32x4 acc0[NT8] = {}; f32x4 acc1[NT8] = {};

#define S6_STAGE(BC, KC) do { \
    gload16(asrc[0] + (KC), Ash + (BC)*4096 + slotb[0]); \
    gload16(asrc[1] + (KC), Ash + (BC)*4096 + slotb[1]); \
    gload16(bsrc[0] + (KC), Bsh + (BC)*4096 + slotb[0]); \
    gload16(bsrc[1] + (KC), Bsh + (BC)*4096 + slotb[1]); \
  } while(0)

  const int r0 = w*32 + l15, r1 = r0 + 16;
  const int ao0 = r0*32 + ((g ^ ((r0>>1)&3))<<3);
  const int ao1 = r1*32 + ((g ^ ((r1>>1)&3))<<3);

#define S6_COMPUTE(BC) do { \
    const __bf16* As_ = Ash + (BC)*4096; \
    const __bf16* Bs_ = Bsh + (BC)*4096; \
    bf16x8 a0_ = *(const bf16x8*)(As_ + ao0); \
    bf16x8 a1_ = *(const bf16x8*)(As_ + ao1); \
    _Pragma("unroll") \
    for (int nt_ = 0; nt_ < NT8; nt_++){ \
      int br_ = nt_*16 + l15; \
      bf16x8 b_ = *(const bf16x8*)(Bs_ + br_*32 + ((g ^ ((br_>>1)&3))<<3)); \
      acc0[nt_] = MFMA16(a0_, b_, acc0[nt_]); \
      acc1[nt_] = MFMA16(a1_, b_, acc1[nt_]); \
    } \
  } while(0)

  S6_STAGE(0,0); S6_STAGE(1,32); S6_STAGE(2,64);
  WVM(8); ABAR;
  #pragma unroll
  for (int c = 0; c < 16; c++){
    S6_COMPUTE(c%3);
    if (c < 13){
      ABAR;                      // all waves done reading buf c%3
      S6_STAGE(c%3, (c+3)*32);
      WVM(8); ABAR;              // chunk c+1 loads complete in every wave
    } else if (c == 13){
      WVM(4); ABAR;
    } else if (c == 14){
      WVM(0); ABAR;
    }
  }

  // ---- fused epilogue: partial score over this half's 128 cols, both layers ----
  float wdv[NT8], bav[NT8];
  #pragma unroll
  for (int nt = 0; nt < NT8; nt++){
    int col = half*128 + nt*16 + l15;
    wdv[nt] = wd_pad[col];
    bav[nt] = ba_pad[col];
  }
  #pragma unroll
  for (int mt = 0; mt < 2; mt++){
    #pragma unroll
    for (int r = 0; r < 4; r++){
      int row = rowbase + w*32 + mt*16 + g*4 + r;
      float ah0 = att_h[row];
      float ah1 = att_h[MATT + row];
      float s0 = 0.0f, s1 = 0.0f;
      #pragma unroll
      for (int nt = 0; nt < NT8; nt++){
        float v = (mt ? acc1[nt][r] : acc0[nt][r]) + bav[nt];
        s0 += fast_tanh(v + ah0) * wdv[nt];
        s1 += fast_tanh(v + ah1) * wdv[nt];
      }
      #pragma unroll
      for (int o = 1; o < 16; o <<= 1){
        s0 += __shfl_xor(s0, o, 16);
        s1 += __shfl_xor(s1, o, 16);
      }
      if (l15 == 0){
        sp[(size_t)half*2*MATT + row]        = s0;
        sp[(size_t)half*2*MATT + MATT + row] = s1;
      }
    }
  }
#undef S6_STAGE
#undef S6_COMPUTE
}

// ---------- softmax over 196 positions (sums the two col-half partials) ----------
__global__ void softmax196b_k(const float* __restrict__ sp, float* __restrict__ wsm){
  int lb = blockIdx.x;          // l*256 + b
  int t = threadIdx.x;          // 64
  const float* p = sp + (size_t)(lb>>8)*MATT + (size_t)(lb&255)*AA;
  const float* q = p + (size_t)2*MATT;
  float v0 = (t      < AA) ? p[t]     + q[t]     : -3.4e38f;
  float v1 = (t+64   < AA) ? p[t+64]  + q[t+64]  : -3.4e38f;
  float v2 = (t+128  < AA) ? p[t+128] + q[t+128] : -3.4e38f;
  float v3 = (t+192  < AA) ? p[t+192] + q[t+192] : -3.4e38f;
  float mx = fmaxf(fmaxf(v0,v1), fmaxf(v2,v3));
  #pragma unroll
  for (int o = 1; o < 64; o <<= 1) mx = fmaxf(mx, __shfl_xor(mx, o, 64));
  float e0 = (t      < AA) ? __expf(v0 - mx) : 0.0f;
  float e1 = (t+64   < AA) ? __expf(v1 - mx) : 0.0f;
  float e2 = (t+128  < AA) ? __expf(v2 - mx) : 0.0f;
  float e3 = (t+192  < AA) ? __expf(v3 - mx) : 0.0f;
  float sum = e0+e1+e2+e3;
  #pragma unroll
  for (int o = 1; o < 64; o <<= 1) sum += __shfl_xor(sum, o, 64);
  float inv = 1.0f / sum;
  float* o_ = wsm + (size_t)lb*AA;
  if (t      < AA) o_[t]     = e0*inv;
  if (t+64   < AA) o_[t+64]  = e1*inv;
  if (t+128  < AA) o_[t+128] = e2*inv;
  if (t+192  < AA) o_[t+192] = e3*inv;
}

// ---------- att_res (bf16 att, both layers) + Xcat fills ----------
__global__ __launch_bounds__(512) void attres4_k(
    const __bf16* __restrict__ att_bf, const float* __restrict__ wsm,
    const float* __restrict__ x, const float* __restrict__ inputs,
    __bf16* __restrict__ Xcat0, __bf16* __restrict__ Xcat1){
  int b = blockIdx.x, t = threadIdx.x;  // 512 threads
  __shared__ float w0[AA+4], w1[AA+4];
  __shared__ float red[8][520];
  if (t < AA) w0[t] = wsm[(size_t)b*AA + t];
  int t2 = t - 256;
  if (t2 >= 0 && t2 < AA) w1[t2] = wsm[(size_t)(256+b)*AA + t2];
  Xcat0[(size_t)b*1536 + t]       = (__bf16)x[(size_t)b*512 + t];
  Xcat0[(size_t)b*1536 + 512 + t] = (__bf16)inputs[(size_t)1*131072 + b*512 + t];
  Xcat1[(size_t)b*1536 + 512 + t] = (__bf16)inputs[(size_t)3*131072 + b*512 + t];
  __syncthreads();
  int cg = t & 63, ig = t >> 6;
  const __bf16* ap = att_bf + (size_t)b*AA*RR + cg*8;
  float s0[8] = {}, s1[8] = {};
  for (int i = ig; i < AA; i += 8){
    bf16x8 v = *(const bf16x8*)(ap + (size_t)i*RR);
    float a0 = w0[i], a1 = w1[i];
    #pragma unroll
    for (int e = 0; e < 8; e++){
      float f = (float)v[e];
      s0[e] += f*a0; s1[e] += f*a1;
    }
  }
  #pragma unroll
  for (int e = 0; e < 8; e++) red[ig][cg*8+e] = s0[e];
  __syncthreads();
  {
    float a = 0;
    #pragma unroll
    for (int q = 0; q < 8; q++) a += red[q][t];
    Xcat0[(size_t)b*1536 + 1024 + t] = (__bf16)a;
  }
  __syncthreads();
  #pragma unroll
  for (int e = 0; e < 8; e++) red[ig][cg*8+e] = s1[e];
  __syncthreads();
  {
    float a = 0;
    #pragma unroll
    for (int q = 0; q < 8; q++) a += red[q][t];
    Xcat1[(size_t)b*1536 + 1024 + t] = (__bf16)a;
  }
}

// ---------- LSTM gates ----------
__global__ void gate_k(const float* __restrict__ sums, const float* __restrict__ prev_c,
                       float* __restrict__ out_c, float* __restrict__ out_h,
                       __bf16* __restrict__ hdst, int hstride){
  int idx = blockIdx.x*256 + threadIdx.x;  // < 131072
  int b = idx >> 9, r = idx & 511;
  const float* s = sums + (size_t)b*2048;
  float ig = 1.0f/(1.0f + __expf(-s[r]));
  float fg = 1.0f/(1.0f + __expf(-s[512+r]));
  float og = 1.0f/(1.0f + __expf(-s[1024+r]));
  float g  = fast_tanh(s[1536+r]);
  float c = fg*prev_c[idx] + ig*g;
  float h = og*fast_tanh(c);
  out_c[idx] = c;
  out_h[idx] = h;
  hdst[(size_t)b*hstride + r] = (__bf16)h;
}

// ---------- log_softmax over V=10000, one block per b ----------
__global__ void logsoftmax_k(const float* __restrict__ logits, float* __restrict__ out){
  int b = blockIdx.x, t = threadIdx.x;  // 256 threads
  __shared__ float red[4], red2[4];
  const float* p = logits + (size_t)b*VV;
  float mx = -3.4e38f;
  for (int i = t; i < VV; i += 256) mx = fmaxf(mx, p[i]);
  #pragma unroll
  for (int o = 1; o < 64; o <<= 1) mx = fmaxf(mx, __shfl_xor(mx, o, 64));
  if ((t & 63) == 0) red[t >> 6] = mx;
  __syncthreads();
  mx = fmaxf(fmaxf(red[0], red[1]), fmaxf(red[2], red[3]));
  float sum = 0.0f;
  for (int i = t; i < VV; i += 256) sum += __expf(p[i] - mx);
  #pragma unroll
  for (int o = 1; o < 64; o <<= 1) sum += __shfl_xor(sum, o, 64);
  if ((t & 63) == 0) red2[t >> 6] = sum;
  __syncthreads();
  sum = red2[0] + red2[1] + red2[2] + red2[3];
  float lse = mx + logf(sum);
  float* q = out + (size_t)b*VV;
  for (int i = t; i < VV; i += 256) q[i] = p[i] - lse;
}

extern "C" void kernel_launch(void* const* d_in, const int* in_sizes, int n_in,
                              void* d_out_, int out_size, void* d_ws, size_t ws_size,
                              hipStream_t stream){
  const float* x     = (const float*)d_in[0];
  const float* att   = (const float*)d_in[1];
  const float* inputs= (const float*)d_in[2];
  const float* Wa2a  = (const float*)d_in[3];
  const float* ba2a  = (const float*)d_in[4];
  const float* Wh2a  = (const float*)d_in[5];
  const float* bh2a  = (const float*)d_in[6];
  const float* wd2d  = (const float*)d_in[7];
  // d_in[8] = bd2d : uniform pre-softmax scalar -> softmax-invariant, unused
  const float* Wi2h  = (const float*)d_in[9];
  const float* bi2h  = (const float*)d_in[10];
  const float* Wh2h  = (const float*)d_in[11];
  const float* bh2h  = (const float*)d_in[12];
  const float* Wr2a  = (const float*)d_in[13];
  const float* br2a  = (const float*)d_in[14];
  const float* Wproj = (const float*)d_in[15];
  const float* bproj = (const float*)d_in[16];
  float* d_out = (float*)d_out_;

  char* wsp = (char*)d_ws;
  auto alloc = [&](size_t bytes)->char*{
    char* p = wsp;
    wsp += (bytes + 255) & ~(size_t)255;
    return p;
  };
  __bf16* att_bf   = (__bf16*)alloc((size_t)MATT*RR*2);    // 51.4 MB
  __bf16* Wa2a_p   = (__bf16*)alloc((size_t)256*RR*2);     // [256][512], zero-pad rows
  __bf16* Wh2a_pad = (__bf16*)alloc((size_t)256*RR*2);
  __bf16* Wcat_bf  = (__bf16*)alloc((size_t)2048*1536*2);
  __bf16* Wproj_bf = (__bf16*)alloc((size_t)10048*RR*2);
  __bf16* inp_bf   = (__bf16*)alloc((size_t)512*RR*2);
  float* ba_pad = (float*)alloc(256*4);
  float* wd_pad = (float*)alloc(256*4);
  float* bcat   = (float*)alloc(2048*4);
  float* att_h  = (float*)alloc((size_t)2*MATT*4);
  float* sp     = (float*)alloc((size_t)4*MATT*4);         // [half][layer][MATT]
  float* wsm    = (float*)alloc((size_t)2*MATT*4);
  __bf16* Xcat0 = (__bf16*)alloc((size_t)BB*1536*2);
  __bf16* Xcat1 = (__bf16*)alloc((size_t)BB*1536*2);
  float* sums   = (float*)alloc((size_t)BB*2048*4);
  __bf16* h1_bf = (__bf16*)alloc((size_t)BB*RR*2);
  float* logits = (float*)alloc((size_t)BB*VV*4);

  // prep
  cvt4_k<<<(MATT*RR/4)/256, 256, 0, stream>>>(att, att_bf, MATT*RR/4);
  cvt_padrows_k<<<(256*512)/256, 256, 0, stream>>>(Wa2a, Wa2a_p, AA);
  cvt_padrows_k<<<(256*512)/256, 256, 0, stream>>>(Wh2a, Wh2a_pad, AA);
  cvt_padrows_k<<<(10048*512)/256, 256, 0, stream>>>(Wproj, Wproj_bf, VV);
  cvt4_k<<<(131072/4)/256, 256, 0, stream>>>(inputs + 1*131072, inp_bf, 131072/4);
  cvt4_k<<<(131072/4)/256, 256, 0, stream>>>(inputs + 3*131072, inp_bf + 131072, 131072/4);
  wcat2_k<<<dim3(6,2048), 256, 0, stream>>>(Wi2h, Wh2h, Wr2a, Wcat_bf);
  build_small_k<<<10, 256, 0, stream>>>(ba2a, wd2d, bi2h, bh2h, br2a, ba_pad, wd_pad, bcat);

  // att_h for both layers (fixed inputs): [512 rows][196]
  gemm3_k<<<dim3(4,16), 256, 0, stream>>>(inp_bf, Wh2a_pad, bh2a, att_h, AA, 512, 8);
  att_score6_k<<<dim3(392,2), 256, 0, stream>>>(att_bf, Wa2a_p, ba_pad, wd_pad, att_h, sp);
  softmax196b_k<<<512, 64, 0, stream>>>(sp, wsm);
  attres4_k<<<256, 512, 0, stream>>>(att_bf, wsm, x, inputs, Xcat0, Xcat1);

  // layer 0
  gemm3_k<<<dim3(32,8), 256, 0, stream>>>(Xcat0, Wcat_bf, bcat, sums, 2048, 1536, 24);
  gate_k<<<512, 256, 0, stream>>>(sums, inputs, d_out, d_out + 131072, Xcat1, 1536);
  // layer 1
  gemm3_k<<<dim3(32,8), 256, 0, stream>>>(Xcat1, Wcat_bf, bcat, sums, 2048, 1536, 24);
  gate_k<<<512, 256, 0, stream>>>(sums, inputs + 2*131072, d_out + 2*131072, d_out + 3*131072, h1_bf, 512);

  // projection + log_softmax
  gemm3_k<<<dim3(157,8), 256, 0, stream>>>(h1_bf, Wproj_bf, bproj, logits, VV, 512, 8);
  logsoftmax_k<<<256, 256, 0, stream>>>(logits, d_out + 4*131072);
}

// Round 7
// 167.310 us; speedup vs baseline: 1.0845x; 1.0845x over previous
//
#include <hip/hip_runtime.h>
#include <hip/hip_bf16.h>
#include <cstdint>
#include <cstddef>

#define BB 256
#define RR 512
#define AA 196
#define VV 10000
#define MATT (BB*AA)   // 50176

typedef float f32x4 __attribute__((ext_vector_type(4)));
typedef __bf16 bf16x8 __attribute__((ext_vector_type(8)));
typedef __bf16 bf16x4 __attribute__((ext_vector_type(4)));

#define MFMA16(a,b,c) __builtin_amdgcn_mfma_f32_16x16x32_bf16(a,b,c,0,0,0)

__device__ __forceinline__ float fast_tanh(float x){
  float ax = fabsf(x);
  float e = __expf(-2.0f*ax);
  float t = __fdividef(1.0f - e, 1.0f + e);
  return x < 0.0f ? -t : t;
}

// async global -> LDS, 16B per lane (LDS dest must be wave-uniform; HW adds lane*16)
__device__ __forceinline__ void gload16(const void* gsrc, void* ldsdst){
  __builtin_amdgcn_global_load_lds(
      (const __attribute__((address_space(1))) unsigned int*)gsrc,
      (__attribute__((address_space(3))) unsigned int*)ldsdst,
      16, 0, 0);
}

#define ABAR   asm volatile("s_barrier" ::: "memory")
#define WVM(N) asm volatile("s_waitcnt vmcnt(" #N ")" ::: "memory")

#define CVT8(a, f0, f1) do { \
  a[0]=(__bf16)(f0).x; a[1]=(__bf16)(f0).y; a[2]=(__bf16)(f0).z; a[3]=(__bf16)(f0).w; \
  a[4]=(__bf16)(f1).x; a[5]=(__bf16)(f1).y; a[6]=(__bf16)(f1).z; a[7]=(__bf16)(f1).w; \
} while(0)

// ---------- weight/input prep ----------
__global__ void cvt4_k(const float* __restrict__ src, __bf16* __restrict__ dst, int n4){
  int i = blockIdx.x*256 + threadIdx.x;
  if (i < n4){
    float4 v = ((const float4*)src)[i];
    bf16x4 o;
    o[0]=(__bf16)v.x; o[1]=(__bf16)v.y; o[2]=(__bf16)v.z; o[3]=(__bf16)v.w;
    ((bf16x4*)dst)[i] = o;
  }
}

// [total][512] bf16, rows >= nvalid zeroed. grid covers total*512.
__global__ void cvt_padrows_k(const float* __restrict__ src, __bf16* __restrict__ dst, int nvalid){
  int i = blockIdx.x*256 + threadIdx.x;
  int row = i >> 9;
  dst[i] = (__bf16)((row < nvalid) ? src[(size_t)row*512 + (i & 511)] : 0.0f);
}

__global__ void wcat2_k(const float* __restrict__ Wi2h, const float* __restrict__ Wh2h,
                        const float* __restrict__ Wr2a, __bf16* __restrict__ Wcat){
  int k = blockIdx.x*256 + threadIdx.x;   // 0..1535
  int n = blockIdx.y;                     // 0..2047
  float v;
  if (k < 512)       v = Wi2h[n*512 + k];
  else if (k < 1024) v = Wh2h[n*512 + (k-512)];
  else               v = Wr2a[n*512 + (k-1024)];
  Wcat[(size_t)n*1536 + k] = (__bf16)v;
}

__global__ void build_small_k(const float* __restrict__ ba2a, const float* __restrict__ wd2d,
                              const float* __restrict__ bi2h, const float* __restrict__ bh2h,
                              const float* __restrict__ br2a,
                              float* __restrict__ ba_pad, float* __restrict__ wd_pad,
                              float* __restrict__ bcat){
  int i = blockIdx.x*256 + threadIdx.x;
  if (i < 2048){
    bcat[i] = bi2h[i] + bh2h[i] + br2a[i];
  } else if (i < 2048+256){
    int j = i - 2048; ba_pad[j] = (j < AA) ? ba2a[j] : 0.0f;
  } else if (i < 2048+512){
    int j = i - 2304; wd_pad[j] = (j < AA) ? wd2d[j] : 0.0f;
  }
}

// ---------- pipelined bf16 GEMM: C[m][n] = sum_k A[m][k]*W[n][k] + bias[n] ----------
// BM=32, BN=64, K-chunk=64, 4 waves, 3-buffer LDS, counted vmcnt.
__global__ __launch_bounds__(256,4) void gemm3_k(
    const __bf16* __restrict__ A, const __bf16* __restrict__ Bw,
    const float* __restrict__ bias, float* __restrict__ C,
    int N, int K, int NC)
{
  __shared__ __bf16 AshAll[3*2048];   // 3 x 32x64
  __shared__ __bf16 BshAll[3*4096];   // 3 x 64x64
  const int t = threadIdx.x;
  const int l = t & 63;
  const int w = t >> 6;
  const int l15 = l & 15;
  const int g  = l >> 4;
  const int rho = l15 & 7;
  const int mrow = blockIdx.y*32;
  const int ncb  = blockIdx.x*64;

  const int arow = t >> 3, aj = t & 7;
  const __bf16* as_ = A + (size_t)(mrow + arow)*K + ((aj ^ (arow&7)) << 3);
  const int aoff = w*512;
  const __bf16* bs0_ = Bw + (size_t)(ncb + arow)*K      + ((aj ^ (arow&7)) << 3);
  const __bf16* bs1_ = Bw + (size_t)(ncb + 32 + arow)*K + ((aj ^ (arow&7)) << 3);
  const int boff0 = w*512;
  const int boff1 = 2048 + w*512;

#define G3_STAGE(B, CH) do { \
    gload16(as_  + (CH)*64, AshAll + (B)*2048 + aoff); \
    gload16(bs0_ + (CH)*64, BshAll + (B)*4096 + boff0); \
    gload16(bs1_ + (CH)*64, BshAll + (B)*4096 + boff1); \
  } while(0)

  f32x4 acc0 = {}, acc1 = {};

#define G3_COMPUTE(B) do { \
    const __bf16* As_ = AshAll + (B)*2048; \
    const __bf16* Bs_ = BshAll + (B)*4096; \
    _Pragma("unroll") \
    for (int s_ = 0; s_ < 2; s_++){ \
      int q_ = (((s_<<2)+g) ^ rho) << 3; \
      bf16x8 a0_ = *(const bf16x8*)(As_ + l15*64 + q_); \
      bf16x8 a1_ = *(const bf16x8*)(As_ + (l15+16)*64 + q_); \
      bf16x8 b_  = *(const bf16x8*)(Bs_ + (w*16+l15)*64 + q_); \
      acc0 = MFMA16(a0_, b_, acc0); \
      acc1 = MFMA16(a1_, b_, acc1); \
    } \
  } while(0)

  G3_STAGE(0,0); G3_STAGE(1,1); G3_STAGE(2,2);
  WVM(6); ABAR;
  int buf = 0;
  for (int c = 0; c < NC; c++){
    G3_COMPUTE(buf);
    if (c + 3 < NC){
      ABAR;
      G3_STAGE(buf, c+3);
      WVM(6); ABAR;
    } else if (c == NC-3){
      WVM(3); ABAR;
    } else if (c == NC-2){
      WVM(0); ABAR;
    }
    buf = (buf == 2) ? 0 : buf + 1;
  }

  int col = ncb + w*16 + l15;
  if (col < N){
    float bv = bias[col];
    #pragma unroll
    for (int r = 0; r < 4; r++){
      C[(size_t)(mrow + g*4 + r)*N + col]      = acc0[r] + bv;
      C[(size_t)(mrow + 16 + g*4 + r)*N + col] = acc1[r] + bv;
    }
  }
#undef G3_STAGE
#undef G3_COMPUTE
}

// ---------- attfull: per-b fused attention (score GEMM + softmax + att_res + Xcat fill) ----------
// grid = 256 (one block per b, one block per CU, 1.0 generations), 512 threads = 8 waves (2x4).
// Score GEMM: rows 256-pad (196 real att rows i), cols 256-pad (196 real a), K=512 in 16 chunks of 32.
// A: att f32 -> regs -> cvt bf16 -> LDS (double buffered). B: Wa2a_p bf16 -> regs -> LDS.
// Epilogue: tanh(. + ba + ah[i]).wd2d partial per wave-col -> LDS reduce -> in-block softmax
// -> att_res = sum_i w_i att[b,i,:] (re-read att[b] f32 from L2/L3) -> Xcat0/1 bf16.
__global__ __launch_bounds__(512,2) void attfull_k(
    const float* __restrict__ att, const __bf16* __restrict__ Wa2a_p,
    const float* __restrict__ ba_pad, const float* __restrict__ wd_pad,
    const float* __restrict__ att_h, const float* __restrict__ x,
    const float* __restrict__ inputs,
    __bf16* __restrict__ Xcat0, __bf16* __restrict__ Xcat1)
{
  __shared__ char smem[67584];   // [0,16K)x2 = A bufs; [32K,48K)x2 = B bufs; [64K,66K) = ahsh
  const int t = threadIdx.x;
  const int b = blockIdx.x;
  const int l = t & 63;
  const int w = t >> 6;
  const int wr = w >> 2, wc = w & 3;
  const int l15 = l & 15, g = l >> 4;

  // ---- prologue: Xcat fills + att_h preload (overlap with K-loop loads) ----
  Xcat0[(size_t)b*1536 + t]       = (__bf16)x[(size_t)b*512 + t];
  Xcat0[(size_t)b*1536 + 512 + t] = (__bf16)inputs[(size_t)1*131072 + b*512 + t];
  Xcat1[(size_t)b*1536 + 512 + t] = (__bf16)inputs[(size_t)3*131072 + b*512 + t];
  float* ahsh = (float*)(smem + 65536);   // [2][256]
  { int li = t >> 8, i = t & 255;
    ahsh[li*256 + i] = (i < AA) ? att_h[((size_t)li*256 + b)*AA + i] : 0.0f; }

  // ---- staging descriptors: thread t -> (row sr = t>>1, half sh = t&1) covers 16 k ----
  const int sr = t >> 1, sh = t & 1;
  const float*  aSrc = att + ((size_t)b*AA + (sr < AA ? sr : AA-1))*RR + sh*16;
  const __bf16* bSrc = Wa2a_p + (size_t)sr*RR + sh*16;
  const int rb = sr*64;                         // row byte base in [256][32] bf16 tile
  const int q0 = (((sh*2)   ^ (sr&3))<<4);      // swizzled 16B-quad offsets
  const int q1 = (((sh*2+1) ^ (sr&3))<<4);

  f32x4 acc[8][4] = {};
  float4 af0, af1, af2, af3;
  uint4  bq0, bq1;

  const int aswz  = (g ^ (l15&3)) << 4;
  const int abase = (wr*128 + l15)*64 + aswz;   // + rt*1024
  const int bbase = (wc*64  + l15)*64 + aswz;   // + ct*1024

#define AF_LOADP(KC) do { \
    af0 = *(const float4*)(aSrc + (KC));      af1 = *(const float4*)(aSrc + (KC) + 4); \
    af2 = *(const float4*)(aSrc + (KC) + 8);  af3 = *(const float4*)(aSrc + (KC) + 12); \
    bq0 = *(const uint4*)(bSrc + (KC));       bq1 = *(const uint4*)(bSrc + (KC) + 8); \
  } while(0)

#define STAGE_WR(BUF) do { \
    char* Ab = smem + (BUF)*16384; \
    char* Bb = smem + 32768 + (BUF)*16384; \
    bf16x8 w0_, w1_; CVT8(w0_, af0, af1); CVT8(w1_, af2, af3); \
    *(bf16x8*)(Ab + rb + q0) = w0_; \
    *(bf16x8*)(Ab + rb + q1) = w1_; \
    *(uint4*)(Bb + rb + q0) = bq0; \
    *(uint4*)(Bb + rb + q1) = bq1; \
  } while(0)

#define K_COMPUTE(BUF) do { \
    const char* Ab = smem + (BUF)*16384; \
    const char* Bb = smem + 32768 + (BUF)*16384; \
    bf16x8 bfr[4]; \
    _Pragma("unroll") \
    for (int ct = 0; ct < 4; ct++) bfr[ct] = *(const bf16x8*)(Bb + bbase + ct*1024); \
    _Pragma("unroll") \
    for (int rt = 0; rt < 8; rt++){ \
      bf16x8 afr = *(const bf16x8*)(Ab + abase + rt*1024); \
      _Pragma("unroll") \
      for (int ct = 0; ct < 4; ct++) acc[rt][ct] = MFMA16(afr, bfr[ct], acc[rt][ct]); \
    } \
  } while(0)

  AF_LOADP(0);
  STAGE_WR(0);
  AF_LOADP(32);
  __syncthreads();
  #pragma unroll
  for (int c = 0; c < 16; c++){
    K_COMPUTE(c & 1);
    if (c < 15) STAGE_WR((c+1) & 1);
    if (c < 14) AF_LOADP((c+2)*32);
    __syncthreads();
  }

  // ---- epilogue 1: tanh partials over this wave's 64 cols, both layers ----
  float bav[4], wdv[4];
  #pragma unroll
  for (int ct = 0; ct < 4; ct++){
    int col = wc*64 + ct*16 + l15;
    bav[ct] = ba_pad[col];
    wdv[ct] = wd_pad[col];   // 0 for col >= 196 -> pad cols contribute 0
  }
  float* spart = (float*)smem;   // [2][4][256] (chunk bufs dead after final sync)
  #pragma unroll
  for (int rt = 0; rt < 8; rt++){
    #pragma unroll
    for (int rg = 0; rg < 4; rg++){
      int row = wr*128 + rt*16 + g*4 + rg;
      float ah0 = ahsh[row];
      float ah1 = ahsh[256 + row];
      float s0 = 0.0f, s1 = 0.0f;
      #pragma unroll
      for (int ct = 0; ct < 4; ct++){
        float v = acc[rt][ct][rg] + bav[ct];
        s0 += fast_tanh(v + ah0) * wdv[ct];
        s1 += fast_tanh(v + ah1) * wdv[ct];
      }
      #pragma unroll
      for (int o = 1; o < 16; o <<= 1){
        s0 += __shfl_xor(s0, o, 16);
        s1 += __shfl_xor(s1, o, 16);
      }
      if (l15 == 0 && row < AA){
        spart[(0*4 + wc)*256 + row] = s0;
        spart[(1*4 + wc)*256 + row] = s1;
      }
    }
  }
  __syncthreads();

  // ---- epilogue 2: softmax per layer (wave 0 -> layer 0, wave 1 -> layer 1) ----
  float* wv = (float*)(smem + 10240);   // [2][256]
  if (w < 2){
    const float* sl = spart + w*4*256;
    float v0_[4]; float e_[4];
    #pragma unroll
    for (int j = 0; j < 4; j++){
      int i = l + j*64;
      float s = sl[i] + sl[256+i] + sl[512+i] + sl[768+i];
      v0_[j] = (i < AA) ? s : -3.4e38f;
    }
    float mx = fmaxf(fmaxf(v0_[0],v0_[1]), fmaxf(v0_[2],v0_[3]));
    #pragma unroll
    for (int o = 1; o < 64; o <<= 1) mx = fmaxf(mx, __shfl_xor(mx, o, 64));
    float sum = 0.0f;
    #pragma unroll
    for (int j = 0; j < 4; j++){
      int i = l + j*64;
      e_[j] = (i < AA) ? __expf(v0_[j] - mx) : 0.0f;
      sum += e_[j];
    }
    #pragma unroll
    for (int o = 1; o < 64; o <<= 1) sum += __shfl_xor(sum, o, 64);
    float inv = 1.0f / sum;
    #pragma unroll
    for (int j = 0; j < 4; j++){
      int i = l + j*64;
      if (i < AA) wv[w*256 + i] = e_[j]*inv;
    }
  }
  __syncthreads();

  // ---- epilogue 3: att_res = sum_i w_i * att[b,i,:], both layers (att[b] from L2/L3) ----
  int r4 = t & 127, ig = t >> 7;
  const float4* ap = (const float4*)(att + (size_t)b*AA*RR) + r4;
  float4 s0 = {0,0,0,0}, s1 = {0,0,0,0};
  for (int i = ig; i < AA; i += 4){
    float4 v = ap[(size_t)i*128];
    float w0_ = wv[i], w1_ = wv[256+i];
    s0.x += v.x*w0_; s0.y += v.y*w0_; s0.z += v.z*w0_; s0.w += v.w*w0_;
    s1.x += v.x*w1_; s1.y += v.y*w1_; s1.z += v.z*w1_; s1.w += v.w*w1_;
  }
  float4* redv = (float4*)smem;   // [4][128] = 8KB (spart dead, wv at 10240 untouched)
  redv[ig*128 + r4] = s0;
  __syncthreads();
  if (t < 128){
    float4 a = redv[t], b4 = redv[128+t], c4 = redv[256+t], d4 = redv[384+t];
    bf16x4 o;
    o[0]=(__bf16)(a.x+b4.x+c4.x+d4.x); o[1]=(__bf16)(a.y+b4.y+c4.y+d4.y);
    o[2]=(__bf16)(a.z+b4.z+c4.z+d4.z); o[3]=(__bf16)(a.w+b4.w+c4.w+d4.w);
    *(bf16x4*)(Xcat0 + (size_t)b*1536 + 1024 + t*4) = o;
  }
  __syncthreads();
  redv[ig*128 + r4] = s1;
  __syncthreads();
  if (t < 128){
    float4 a = redv[t], b4 = redv[128+t], c4 = redv[256+t], d4 = redv[384+t];
    bf16x4 o;
    o[0]=(__bf16)(a.x+b4.x+c4.x+d4.x); o[1]=(__bf16)(a.y+b4.y+c4.y+d4.y);
    o[2]=(__bf16)(a.z+b4.z+c4.z+d4.z); o[3]=(__bf16)(a.w+b4.w+c4.w+d4.w);
    *(bf16x4*)(Xcat1 + (size_t)b*1536 + 1024 + t*4) = o;
  }
#undef AF_LOADP
#undef STAGE_WR
#undef K_COMPUTE
}

// ---------- LSTM gates ----------
__global__ void gate_k(const float* __restrict__ sums, const float* __restrict__ prev_c,
                       float* __restrict__ out_c, float* __restrict__ out_h,
                       __bf16* __restrict__ hdst, int hstride){
  int idx = blockIdx.x*256 + threadIdx.x;  // < 131072
  int b = idx >> 9, r = idx & 511;
  const float* s = sums + (size_t)b*2048;
  float ig = 1.0f/(1.0f + __expf(-s[r]));
  float fg = 1.0f/(1.0f + __expf(-s[512+r]));
  float og = 1.0f/(1.0f + __expf(-s[1024+r]));
  float g  = fast_tanh(s[1536+r]);
  float c = fg*prev_c[idx] + ig*g;
  float h = og*fast_tanh(c);
  out_c[idx] = c;
  out_h[idx] = h;
  hdst[(size_t)b*hstride + r] = (__bf16)h;
}

// ---------- log_softmax over V=10000, one block per b ----------
__global__ void logsoftmax_k(const float* __restrict__ logits, float* __restrict__ out){
  int b = blockIdx.x, t = threadIdx.x;  // 256 threads
  __shared__ float red[4], red2[4];
  const float* p = logits + (size_t)b*VV;
  float mx = -3.4e38f;
  for (int i = t; i < VV; i += 256) mx = fmaxf(mx, p[i]);
  #pragma unroll
  for (int o = 1; o < 64; o <<= 1) mx = fmaxf(mx, __shfl_xor(mx, o, 64));
  if ((t & 63) == 0) red[t >> 6] = mx;
  __syncthreads();
  mx = fmaxf(fmaxf(red[0], red[1]), fmaxf(red[2], red[3]));
  float sum = 0.0f;
  for (int i = t; i < VV; i += 256) sum += __expf(p[i] - mx);
  #pragma unroll
  for (int o = 1; o < 64; o <<= 1) sum += __shfl_xor(sum, o, 64);
  if ((t & 63) == 0) red2[t >> 6] = sum;
  __syncthreads();
  sum = red2[0] + red2[1] + red2[2] + red2[3];
  float lse = mx + logf(sum);
  float* q = out + (size_t)b*VV;
  for (int i = t; i < VV; i += 256) q[i] = p[i] - lse;
}

extern "C" void kernel_launch(void* const* d_in, const int* in_sizes, int n_in,
                              void* d_out_, int out_size, void* d_ws, size_t ws_size,
                              hipStream_t stream){
  const float* x     = (const float*)d_in[0];
  const float* att   = (const float*)d_in[1];
  const float* inputs= (const float*)d_in[2];
  const float* Wa2a  = (const float*)d_in[3];
  const float* ba2a  = (const float*)d_in[4];
  const float* Wh2a  = (const float*)d_in[5];
  const float* bh2a  = (const float*)d_in[6];
  const float* wd2d  = (const float*)d_in[7];
  // d_in[8] = bd2d : uniform pre-softmax scalar -> softmax-invariant, unused
  const float* Wi2h  = (const float*)d_in[9];
  const float* bi2h  = (const float*)d_in[10];
  const float* Wh2h  = (const float*)d_in[11];
  const float* bh2h  = (const float*)d_in[12];
  const float* Wr2a  = (const float*)d_in[13];
  const float* br2a  = (const float*)d_in[14];
  const float* Wproj = (const float*)d_in[15];
  const float* bproj = (const float*)d_in[16];
  float* d_out = (float*)d_out_;

  char* wsp = (char*)d_ws;
  auto alloc = [&](size_t bytes)->char*{
    char* p = wsp;
    wsp += (bytes + 255) & ~(size_t)255;
    return p;
  };
  __bf16* Wa2a_p   = (__bf16*)alloc((size_t)256*RR*2);     // [256][512], zero-pad rows
  __bf16* Wh2a_pad = (__bf16*)alloc((size_t)256*RR*2);
  __bf16* Wcat_bf  = (__bf16*)alloc((size_t)2048*1536*2);
  __bf16* Wproj_bf = (__bf16*)alloc((size_t)10048*RR*2);
  __bf16* inp_bf   = (__bf16*)alloc((size_t)512*RR*2);
  float* ba_pad = (float*)alloc(256*4);
  float* wd_pad = (float*)alloc(256*4);
  float* bcat   = (float*)alloc(2048*4);
  float* att_h  = (float*)alloc((size_t)2*MATT*4);
  __bf16* Xcat0 = (__bf16*)alloc((size_t)BB*1536*2);
  __bf16* Xcat1 = (__bf16*)alloc((size_t)BB*1536*2);
  float* sums   = (float*)alloc((size_t)BB*2048*4);
  __bf16* h1_bf = (__bf16*)alloc((size_t)BB*RR*2);
  float* logits = (float*)alloc((size_t)BB*VV*4);

  // prep
  cvt_padrows_k<<<(256*512)/256, 256, 0, stream>>>(Wa2a, Wa2a_p, AA);
  cvt_padrows_k<<<(256*512)/256, 256, 0, stream>>>(Wh2a, Wh2a_pad, AA);
  cvt_padrows_k<<<(10048*512)/256, 256, 0, stream>>>(Wproj, Wproj_bf, VV);
  cvt4_k<<<(131072/4)/256, 256, 0, stream>>>(inputs + 1*131072, inp_bf, 131072/4);
  cvt4_k<<<(131072/4)/256, 256, 0, stream>>>(inputs + 3*131072, inp_bf + 131072, 131072/4);
  wcat2_k<<<dim3(6,2048), 256, 0, stream>>>(Wi2h, Wh2h, Wr2a, Wcat_bf);
  build_small_k<<<10, 256, 0, stream>>>(ba2a, wd2d, bi2h, bh2h, br2a, ba_pad, wd_pad, bcat);

  // att_h for both layers (fixed inputs): [512 rows][196]
  gemm3_k<<<dim3(4,16), 256, 0, stream>>>(inp_bf, Wh2a_pad, bh2a, att_h, AA, 512, 8);

  // the whole attention in one launch
  attfull_k<<<256, 512, 0, stream>>>(att, Wa2a_p, ba_pad, wd_pad, att_h, x, inputs, Xcat0, Xcat1);

  // layer 0
  gemm3_k<<<dim3(32,8), 256, 0, stream>>>(Xcat0, Wcat_bf, bcat, sums, 2048, 1536, 24);
  gate_k<<<512, 256, 0, stream>>>(sums, inputs, d_out, d_out + 131072, Xcat1, 1536);
  // layer 1
  gemm3_k<<<dim3(32,8), 256, 0, stream>>>(Xcat1, Wcat_bf, bcat, sums, 2048, 1536, 24);
  gate_k<<<512, 256, 0, stream>>>(sums, inputs + 2*131072, d_out + 2*131072, d_out + 3*131072, h1_bf, 512);

  // projection + log_softmax
  gemm3_k<<<dim3(157,8), 256, 0, stream>>>(h1_bf, Wproj_bf, bproj, logits, VV, 512, 8);
  logsoftmax_k<<<256, 256, 0, stream>>>(logits, d_out + 4*131072);
}

// Round 8
// 160.358 us; speedup vs baseline: 1.1315x; 1.0434x over previous
//
#include <hip/hip_runtime.h>
#include <hip/hip_bf16.h>
#include <cstdint>
#include <cstddef>

#define BB 256
#define RR 512
#define AA 196
#define VV 10000
#define MATT (BB*AA)   // 50176
#define NT13 13        // 13*16 = 208 cols used (B padded to 256 rows)

typedef float f32x4 __attribute__((ext_vector_type(4)));
typedef __bf16 bf16x8 __attribute__((ext_vector_type(8)));
typedef __bf16 bf16x4 __attribute__((ext_vector_type(4)));

#define MFMA16(a,b,c) __builtin_amdgcn_mfma_f32_16x16x32_bf16(a,b,c,0,0,0)

__device__ __forceinline__ float fast_tanh(float x){
  float ax = fabsf(x);
  float e = __expf(-2.0f*ax);
  float t = __fdividef(1.0f - e, 1.0f + e);
  return x < 0.0f ? -t : t;
}

// async global -> LDS, 16B per lane (LDS dest wave-uniform; HW adds lane*16)
__device__ __forceinline__ void gload16(const void* gsrc, void* ldsdst){
  __builtin_amdgcn_global_load_lds(
      (const __attribute__((address_space(1))) unsigned int*)gsrc,
      (__attribute__((address_space(3))) unsigned int*)ldsdst,
      16, 0, 0);
}

#define ABAR   asm volatile("s_barrier" ::: "memory")
#define WVM(N) asm volatile("s_waitcnt vmcnt(" #N ")" ::: "memory")

#define CVT8(a, f0, f1) do { \
  a[0]=(__bf16)(f0).x; a[1]=(__bf16)(f0).y; a[2]=(__bf16)(f0).z; a[3]=(__bf16)(f0).w; \
  a[4]=(__bf16)(f1).x; a[5]=(__bf16)(f1).y; a[6]=(__bf16)(f1).z; a[7]=(__bf16)(f1).w; \
} while(0)

// ---------- weight/input prep (vectorized) ----------
__global__ void cvt4_k(const float* __restrict__ src, __bf16* __restrict__ dst, int n4){
  int i = blockIdx.x*256 + threadIdx.x;
  if (i < n4){
    float4 v = ((const float4*)src)[i];
    bf16x4 o;
    o[0]=(__bf16)v.x; o[1]=(__bf16)v.y; o[2]=(__bf16)v.z; o[3]=(__bf16)v.w;
    ((bf16x4*)dst)[i] = o;
  }
}

// [total][512] bf16 from [nvalid][512] f32, pad rows zero. i4 covers total*128.
__global__ void cvt_padrows4_k(const float* __restrict__ src, __bf16* __restrict__ dst, int nvalid){
  int i4 = blockIdx.x*256 + threadIdx.x;
  int row = i4 >> 7, k4 = i4 & 127;
  float4 v = {0,0,0,0};
  if (row < nvalid) v = ((const float4*)(src + (size_t)row*512))[k4];
  bf16x4 o;
  o[0]=(__bf16)v.x; o[1]=(__bf16)v.y; o[2]=(__bf16)v.z; o[3]=(__bf16)v.w;
  ((bf16x4*)(dst))[i4] = o;
}

// Wcat[n][1536] = [Wi2h | Wh2h | Wr2a] bf16; 384 threads = k4, grid = 2048 (n)
__global__ void wcat4_k(const float* __restrict__ Wi2h, const float* __restrict__ Wh2h,
                        const float* __restrict__ Wr2a, __bf16* __restrict__ Wcat){
  int k4 = threadIdx.x;     // 0..383
  int n  = blockIdx.x;      // 0..2047
  float4 v;
  if (k4 < 128)      v = ((const float4*)(Wi2h + (size_t)n*512))[k4];
  else if (k4 < 256) v = ((const float4*)(Wh2h + (size_t)n*512))[k4-128];
  else               v = ((const float4*)(Wr2a + (size_t)n*512))[k4-256];
  bf16x4 o;
  o[0]=(__bf16)v.x; o[1]=(__bf16)v.y; o[2]=(__bf16)v.z; o[3]=(__bf16)v.w;
  ((bf16x4*)(Wcat + (size_t)n*1536))[k4] = o;
}

__global__ void build_small_k(const float* __restrict__ ba2a, const float* __restrict__ wd2d,
                              const float* __restrict__ bi2h, const float* __restrict__ bh2h,
                              const float* __restrict__ br2a,
                              float* __restrict__ ba_pad, float* __restrict__ wd_pad,
                              float* __restrict__ bcat){
  int i = blockIdx.x*256 + threadIdx.x;
  if (i < 2048){
    bcat[i] = bi2h[i] + bh2h[i] + br2a[i];
  } else if (i < 2048+256){
    int j = i - 2048; ba_pad[j] = (j < AA) ? ba2a[j] : 0.0f;
  } else if (i < 2048+512){
    int j = i - 2304; wd_pad[j] = (j < AA) ? wd2d[j] : 0.0f;
  }
}

// ---------- pipelined bf16 GEMM: C[m][n] = sum_k A[m][k]*W[n][k] + bias[n] ----------
// BM=32, BN=64, K-chunk=64, 4 waves, 3-buffer LDS, counted vmcnt.
__global__ __launch_bounds__(256,4) void gemm3_k(
    const __bf16* __restrict__ A, const __bf16* __restrict__ Bw,
    const float* __restrict__ bias, float* __restrict__ C,
    int N, int K, int NC)
{
  __shared__ __bf16 AshAll[3*2048];   // 3 x 32x64
  __shared__ __bf16 BshAll[3*4096];   // 3 x 64x64
  const int t = threadIdx.x;
  const int l = t & 63;
  const int w = t >> 6;
  const int l15 = l & 15;
  const int g  = l >> 4;
  const int rho = l15 & 7;
  const int mrow = blockIdx.y*32;
  const int ncb  = blockIdx.x*64;

  const int arow = t >> 3, aj = t & 7;
  const __bf16* as_ = A + (size_t)(mrow + arow)*K + ((aj ^ (arow&7)) << 3);
  const int aoff = w*512;
  const __bf16* bs0_ = Bw + (size_t)(ncb + arow)*K      + ((aj ^ (arow&7)) << 3);
  const __bf16* bs1_ = Bw + (size_t)(ncb + 32 + arow)*K + ((aj ^ (arow&7)) << 3);
  const int boff0 = w*512;
  const int boff1 = 2048 + w*512;

#define G3_STAGE(B, CH) do { \
    gload16(as_  + (CH)*64, AshAll + (B)*2048 + aoff); \
    gload16(bs0_ + (CH)*64, BshAll + (B)*4096 + boff0); \
    gload16(bs1_ + (CH)*64, BshAll + (B)*4096 + boff1); \
  } while(0)

  f32x4 acc0 = {}, acc1 = {};

#define G3_COMPUTE(B) do { \
    const __bf16* As_ = AshAll + (B)*2048; \
    const __bf16* Bs_ = BshAll + (B)*4096; \
    _Pragma("unroll") \
    for (int s_ = 0; s_ < 2; s_++){ \
      int q_ = (((s_<<2)+g) ^ rho) << 3; \
      bf16x8 a0_ = *(const bf16x8*)(As_ + l15*64 + q_); \
      bf16x8 a1_ = *(const bf16x8*)(As_ + (l15+16)*64 + q_); \
      bf16x8 b_  = *(const bf16x8*)(Bs_ + (w*16+l15)*64 + q_); \
      acc0 = MFMA16(a0_, b_, acc0); \
      acc1 = MFMA16(a1_, b_, acc1); \
    } \
  } while(0)

  G3_STAGE(0,0); G3_STAGE(1,1); G3_STAGE(2,2);
  WVM(6); ABAR;
  int buf = 0;
  for (int c = 0; c < NC; c++){
    G3_COMPUTE(buf);
    if (c + 3 < NC){
      ABAR;
      G3_STAGE(buf, c+3);
      WVM(6); ABAR;
    } else if (c == NC-3){
      WVM(3); ABAR;
    } else if (c == NC-2){
      WVM(0); ABAR;
    }
    buf = (buf == 2) ? 0 : buf + 1;
  }

  int col = ncb + w*16 + l15;
  if (col < N){
    float bv = bias[col];
    #pragma unroll
    for (int r = 0; r < 4; r++){
      C[(size_t)(mrow + g*4 + r)*N + col]      = acc0[r] + bv;
      C[(size_t)(mrow + 16 + g*4 + r)*N + col] = acc1[r] + bv;
    }
  }
#undef G3_STAGE
#undef G3_COMPUTE
}

// ---------- att_score8: depth-3 counted-vmcnt, 3 blocks/CU, phase-rotated ----------
// Block: 64 att rows x 208 cols. K=512 in 16 chunks of 32, chunk order rotated per block.
// B: [256][32] bf16 chunks in 3x16KB LDS (4 gload_lds/thread/chunk, uniform).
// A: per-wave register fragments (2 flat float4/lane/chunk, 3 sets).
// 6 VMEM/wave/chunk -> vmcnt(12) = exact depth-3 wait.
__global__ __launch_bounds__(256,3) void att_score8_k(
    const float* __restrict__ att, const __bf16* __restrict__ Wa2a_p,
    const float* __restrict__ ba_pad, const float* __restrict__ wd_pad,
    const float* __restrict__ att_h, float* __restrict__ score)
{
  __shared__ __bf16 Bsh[3*8192];   // 3 x [256][32] = 48 KB
  const int t = threadIdx.x;
  const int l = t & 63;
  const int w = t >> 6;
  const int l15 = l & 15, g = l >> 4;

  // XCD-swizzled row-tile (784 = 8*98, bijective) + K-phase rotation
  const int bid = blockIdx.x;
  const int tile = (bid & 7) * 98 + (bid >> 3);
  const int rowbase = tile * 64;
  const int phase = bid & 15;

  // B staging: 1024 slots of 16B; gload i covers slots i*256 + t
  const __bf16* bsrc[4]; int boff[4];
  #pragma unroll
  for (int i = 0; i < 4; i++){
    int slot = i*256 + t;
    int row = slot >> 2, j2 = slot & 3;
    boff[i] = (i*256 + (t & ~63)) * 8;          // wave-uniform elem base
    bsrc[i] = Wa2a_p + (size_t)row*RR + ((j2 ^ (row&3)) << 3);
  }

  // A: lane (g,l15) of wave w covers att[rowbase+w*16+l15][ch*32 + g*8 + 0..7]
  const float* pa = att + (size_t)(rowbase + w*16 + l15)*RR + g*8;

  f32x4 acc[NT13] = {};
  float4 a00,a01, a10,a11, a20,a21;

#define S8_STAGE(BUF, CH) do { \
    int kc_ = (CH)*32; \
    gload16(bsrc[0] + kc_, Bsh + (BUF)*8192 + boff[0]); \
    gload16(bsrc[1] + kc_, Bsh + (BUF)*8192 + boff[1]); \
    gload16(bsrc[2] + kc_, Bsh + (BUF)*8192 + boff[2]); \
    gload16(bsrc[3] + kc_, Bsh + (BUF)*8192 + boff[3]); \
  } while(0)
#define S8_LOADA(S, CH) do { \
    a##S##0 = *(const float4*)(pa + (CH)*32); \
    a##S##1 = *(const float4*)(pa + (CH)*32 + 4); \
  } while(0)
#define S8_COMPUTE(BUF, S) do { \
    bf16x8 a_; CVT8(a_, a##S##0, a##S##1); \
    const __bf16* Bs_ = Bsh + (BUF)*8192; \
    _Pragma("unroll") \
    for (int nt_ = 0; nt_ < NT13; nt_++){ \
      int br_ = nt_*16 + l15; \
      bf16x8 b_ = *(const bf16x8*)(Bs_ + br_*32 + ((g ^ (br_&3))<<3)); \
      acc[nt_] = MFMA16(a_, b_, acc[nt_]); \
    } \
  } while(0)
#define CH(i) (((i) + phase) & 15)

  S8_STAGE(0, CH(0)); S8_LOADA(0, CH(0));
  S8_STAGE(1, CH(1)); S8_LOADA(1, CH(1));
  S8_STAGE(2, CH(2)); S8_LOADA(2, CH(2));
  WVM(12); ABAR;

#define S8_ITER(c, S) do { \
    S8_COMPUTE(S, S); \
    if ((c) < 13){ \
      ABAR; \
      S8_STAGE(S, CH((c)+3)); S8_LOADA(S, CH((c)+3)); \
      WVM(12); ABAR; \
    } else if ((c) == 13){ WVM(6); ABAR; } \
    else if ((c) == 14){ WVM(0); ABAR; } \
  } while(0)

  S8_ITER(0,0);  S8_ITER(1,1);  S8_ITER(2,2);  S8_ITER(3,0);
  S8_ITER(4,1);  S8_ITER(5,2);  S8_ITER(6,0);  S8_ITER(7,1);
  S8_ITER(8,2);  S8_ITER(9,0);  S8_ITER(10,1); S8_ITER(11,2);
  S8_ITER(12,0); S8_ITER(13,1); S8_ITER(14,2); S8_ITER(15,0);

  // ---- fused epilogue: tanh(acc + ba + att_h) . wd2d, both layers ----
  float wdv[NT13], bav[NT13];
  #pragma unroll
  for (int nt = 0; nt < NT13; nt++){
    int col = nt*16 + l15;
    wdv[nt] = wd_pad[col];
    bav[nt] = ba_pad[col];
  }
  #pragma unroll
  for (int r = 0; r < 4; r++){
    int row = rowbase + w*16 + g*4 + r;
    float ah0 = att_h[row];
    float ah1 = att_h[MATT + row];
    float s0 = 0.0f, s1 = 0.0f;
    #pragma unroll
    for (int nt = 0; nt < NT13; nt++){
      float v = acc[nt][r] + bav[nt];
      s0 += fast_tanh(v + ah0) * wdv[nt];
      s1 += fast_tanh(v + ah1) * wdv[nt];
    }
    #pragma unroll
    for (int o = 1; o < 16; o <<= 1){
      s0 += __shfl_xor(s0, o, 16);
      s1 += __shfl_xor(s1, o, 16);
    }
    if (l15 == 0){
      score[row] = s0;
      score[MATT + row] = s1;
    }
  }
#undef S8_STAGE
#undef S8_LOADA
#undef S8_COMPUTE
#undef S8_ITER
#undef CH
}

// ---------- softmax over 196 positions, one wave per (layer,b) ----------
__global__ void softmax196_k(const float* __restrict__ score, float* __restrict__ wsm){
  int lb = blockIdx.x;          // l*256 + b
  int t = threadIdx.x;          // 64
  const float* s = score + (size_t)lb*AA;
  float v0 = (t      < AA) ? s[t]       : -3.4e38f;
  float v1 = (t+64   < AA) ? s[t+64]    : -3.4e38f;
  float v2 = (t+128  < AA) ? s[t+128]   : -3.4e38f;
  float v3 = (t+192  < AA) ? s[t+192]   : -3.4e38f;
  float mx = fmaxf(fmaxf(v0,v1), fmaxf(v2,v3));
  #pragma unroll
  for (int o = 1; o < 64; o <<= 1) mx = fmaxf(mx, __shfl_xor(mx, o, 64));
  float e0 = (t      < AA) ? __expf(v0 - mx) : 0.0f;
  float e1 = (t+64   < AA) ? __expf(v1 - mx) : 0.0f;
  float e2 = (t+128  < AA) ? __expf(v2 - mx) : 0.0f;
  float e3 = (t+192  < AA) ? __expf(v3 - mx) : 0.0f;
  float sum = e0+e1+e2+e3;
  #pragma unroll
  for (int o = 1; o < 64; o <<= 1) sum += __shfl_xor(sum, o, 64);
  float inv = 1.0f / sum;
  float* o_ = wsm + (size_t)lb*AA;
  if (t      < AA) o_[t]     = e0*inv;
  if (t+64   < AA) o_[t+64]  = e1*inv;
  if (t+128  < AA) o_[t+128] = e2*inv;
  if (t+192  < AA) o_[t+192] = e3*inv;
}

// ---------- att_res (both layers, float4 + LDS reduce) + Xcat fills, bf16 out ----------
__global__ __launch_bounds__(512) void attres3_k(
    const float* __restrict__ att, const float* __restrict__ wsm,
    const float* __restrict__ x, const float* __restrict__ inputs,
    __bf16* __restrict__ Xcat0, __bf16* __restrict__ Xcat1){
  int b = blockIdx.x, t = threadIdx.x;  // 512 threads
  __shared__ float w0[208], w1[208];
  __shared__ float4 redv[4][128];
  if (t < AA) w0[t] = wsm[(size_t)b*AA + t];
  int t2 = t - 256;
  if (t2 >= 0 && t2 < AA) w1[t2] = wsm[(size_t)(256+b)*AA + t2];
  Xcat0[(size_t)b*1536 + t]       = (__bf16)x[(size_t)b*512 + t];
  Xcat0[(size_t)b*1536 + 512 + t] = (__bf16)inputs[(size_t)1*131072 + b*512 + t];
  Xcat1[(size_t)b*1536 + 512 + t] = (__bf16)inputs[(size_t)3*131072 + b*512 + t];
  __syncthreads();
  int cg = t & 127, ig = t >> 7;
  const float4* ap = (const float4*)(att + (size_t)b*AA*RR) + cg;
  float4 s0 = {0,0,0,0}, s1 = {0,0,0,0};
  #pragma unroll 4
  for (int i = ig; i < AA; i += 4){
    float4 v = ap[(size_t)i*128];
    float a0 = w0[i], a1 = w1[i];
    s0.x += v.x*a0; s0.y += v.y*a0; s0.z += v.z*a0; s0.w += v.w*a0;
    s1.x += v.x*a1; s1.y += v.y*a1; s1.z += v.z*a1; s1.w += v.w*a1;
  }
  redv[ig][cg] = s0; __syncthreads();
  if (t < 128){
    float4 a = redv[0][t], b4 = redv[1][t], c4 = redv[2][t], d4 = redv[3][t];
    bf16x4 o;
    o[0]=(__bf16)(a.x+b4.x+c4.x+d4.x); o[1]=(__bf16)(a.y+b4.y+c4.y+d4.y);
    o[2]=(__bf16)(a.z+b4.z+c4.z+d4.z); o[3]=(__bf16)(a.w+b4.w+c4.w+d4.w);
    *(bf16x4*)(Xcat0 + (size_t)b*1536 + 1024 + t*4) = o;
  }
  __syncthreads();
  redv[ig][cg] = s1; __syncthreads();
  if (t < 128){
    float4 a = redv[0][t], b4 = redv[1][t], c4 = redv[2][t], d4 = redv[3][t];
    bf16x4 o;
    o[0]=(__bf16)(a.x+b4.x+c4.x+d4.x); o[1]=(__bf16)(a.y+b4.y+c4.y+d4.y);
    o[2]=(__bf16)(a.z+b4.z+c4.z+d4.z); o[3]=(__bf16)(a.w+b4.w+c4.w+d4.w);
    *(bf16x4*)(Xcat1 + (size_t)b*1536 + 1024 + t*4) = o;
  }
}

// ---------- LSTM gates ----------
__global__ void gate_k(const float* __restrict__ sums, const float* __restrict__ prev_c,
                       float* __restrict__ out_c, float* __restrict__ out_h,
                       __bf16* __restrict__ hdst, int hstride){
  int idx = blockIdx.x*256 + threadIdx.x;  // < 131072
  int b = idx >> 9, r = idx & 511;
  const float* s = sums + (size_t)b*2048;
  float ig = 1.0f/(1.0f + __expf(-s[r]));
  float fg = 1.0f/(1.0f + __expf(-s[512+r]));
  float og = 1.0f/(1.0f + __expf(-s[1024+r]));
  float g  = fast_tanh(s[1536+r]);
  float c = fg*prev_c[idx] + ig*g;
  float h = og*fast_tanh(c);
  out_c[idx] = c;
  out_h[idx] = h;
  hdst[(size_t)b*hstride + r] = (__bf16)h;
}

// ---------- log_softmax over V=10000, float4, one block per b ----------
__global__ void logsoftmax4_k(const float* __restrict__ logits, float* __restrict__ out){
  int b = blockIdx.x, t = threadIdx.x;  // 256 threads
  __shared__ float red[4], red2[4];
  const float4* p = (const float4*)(logits + (size_t)b*VV);   // 2500 float4
  float mx = -3.4e38f;
  for (int i = t; i < 2500; i += 256){
    float4 v = p[i];
    mx = fmaxf(mx, fmaxf(fmaxf(v.x,v.y), fmaxf(v.z,v.w)));
  }
  #pragma unroll
  for (int o = 1; o < 64; o <<= 1) mx = fmaxf(mx, __shfl_xor(mx, o, 64));
  if ((t & 63) == 0) red[t >> 6] = mx;
  __syncthreads();
  mx = fmaxf(fmaxf(red[0], red[1]), fmaxf(red[2], red[3]));
  float sum = 0.0f;
  for (int i = t; i < 2500; i += 256){
    float4 v = p[i];
    sum += __expf(v.x-mx) + __expf(v.y-mx) + __expf(v.z-mx) + __expf(v.w-mx);
  }
  #pragma unroll
  for (int o = 1; o < 64; o <<= 1) sum += __shfl_xor(sum, o, 64);
  if ((t & 63) == 0) red2[t >> 6] = sum;
  __syncthreads();
  sum = red2[0] + red2[1] + red2[2] + red2[3];
  float lse = mx + logf(sum);
  float4* q = (float4*)(out + (size_t)b*VV);
  for (int i = t; i < 2500; i += 256){
    float4 v = p[i];
    v.x -= lse; v.y -= lse; v.z -= lse; v.w -= lse;
    q[i] = v;
  }
}

extern "C" void kernel_launch(void* const* d_in, const int* in_sizes, int n_in,
                              void* d_out_, int out_size, void* d_ws, size_t ws_size,
                              hipStream_t stream){
  const float* x     = (const float*)d_in[0];
  const float* att   = (const float*)d_in[1];
  const float* inputs= (const float*)d_in[2];
  const float* Wa2a  = (const float*)d_in[3];
  const float* ba2a  = (const float*)d_in[4];
  const float* Wh2a  = (const float*)d_in[5];
  const float* bh2a  = (const float*)d_in[6];
  const float* wd2d  = (const float*)d_in[7];
  // d_in[8] = bd2d : uniform pre-softmax scalar -> softmax-invariant, unused
  const float* Wi2h  = (const float*)d_in[9];
  const float* bi2h  = (const float*)d_in[10];
  const float* Wh2h  = (const float*)d_in[11];
  const float* bh2h  = (const float*)d_in[12];
  const float* Wr2a  = (const float*)d_in[13];
  const float* br2a  = (const float*)d_in[14];
  const float* Wproj = (const float*)d_in[15];
  const float* bproj = (const float*)d_in[16];
  float* d_out = (float*)d_out_;

  char* wsp = (char*)d_ws;
  auto alloc = [&](size_t bytes)->char*{
    char* p = wsp;
    wsp += (bytes + 255) & ~(size_t)255;
    return p;
  };
  __bf16* Wa2a_p   = (__bf16*)alloc((size_t)256*RR*2);     // [256][512], zero-pad rows
  __bf16* Wh2a_pad = (__bf16*)alloc((size_t)256*RR*2);
  __bf16* Wcat_bf  = (__bf16*)alloc((size_t)2048*1536*2);
  __bf16* Wproj_bf = (__bf16*)alloc((size_t)10048*RR*2);
  __bf16* inp_bf   = (__bf16*)alloc((size_t)512*RR*2);
  float* ba_pad = (float*)alloc(256*4);
  float* wd_pad = (float*)alloc(256*4);
  float* bcat   = (float*)alloc(2048*4);
  float* att_h  = (float*)alloc((size_t)2*MATT*4);
  float* score  = (float*)alloc((size_t)2*MATT*4);
  float* wsm    = (float*)alloc((size_t)2*MATT*4);
  __bf16* Xcat0 = (__bf16*)alloc((size_t)BB*1536*2);
  __bf16* Xcat1 = (__bf16*)alloc((size_t)BB*1536*2);
  float* sums   = (float*)alloc((size_t)BB*2048*4);
  __bf16* h1_bf = (__bf16*)alloc((size_t)BB*RR*2);
  float* logits = (float*)alloc((size_t)BB*VV*4);

  // prep (all vectorized)
  cvt_padrows4_k<<<(256*128)/256, 256, 0, stream>>>(Wa2a, Wa2a_p, AA);
  cvt_padrows4_k<<<(256*128)/256, 256, 0, stream>>>(Wh2a, Wh2a_pad, AA);
  cvt_padrows4_k<<<(10048*128)/256, 256, 0, stream>>>(Wproj, Wproj_bf, VV);
  cvt4_k<<<(131072/4)/256, 256, 0, stream>>>(inputs + 1*131072, inp_bf, 131072/4);
  cvt4_k<<<(131072/4)/256, 256, 0, stream>>>(inputs + 3*131072, inp_bf + 131072, 131072/4);
  wcat4_k<<<2048, 384, 0, stream>>>(Wi2h, Wh2h, Wr2a, Wcat_bf);
  build_small_k<<<10, 256, 0, stream>>>(ba2a, wd2d, bi2h, bh2h, br2a, ba_pad, wd_pad, bcat);

  // att_h for both layers (fixed inputs): [512 rows][196]
  gemm3_k<<<dim3(4,16), 256, 0, stream>>>(inp_bf, Wh2a_pad, bh2a, att_h, AA, 512, 8);

  // attention
  att_score8_k<<<784, 256, 0, stream>>>(att, Wa2a_p, ba_pad, wd_pad, att_h, score);
  softmax196_k<<<512, 64, 0, stream>>>(score, wsm);
  attres3_k<<<256, 512, 0, stream>>>(att, wsm, x, inputs, Xcat0, Xcat1);

  // layer 0
  gemm3_k<<<dim3(32,8), 256, 0, stream>>>(Xcat0, Wcat_bf, bcat, sums, 2048, 1536, 24);
  gate_k<<<512, 256, 0, stream>>>(sums, inputs, d_out, d_out + 131072, Xcat1, 1536);
  // layer 1
  gemm3_k<<<dim3(32,8), 256, 0, stream>>>(Xcat1, Wcat_bf, bcat, sums, 2048, 1536, 24);
  gate_k<<<512, 256, 0, stream>>>(sums, inputs + 2*131072, d_out + 2*131072, d_out + 3*131072, h1_bf, 512);

  // projection + log_softmax
  gemm3_k<<<dim3(157,8), 256, 0, stream>>>(h1_bf, Wproj_bf, bproj, logits, VV, 512, 8);
  logsoftmax4_k<<<256, 256, 0, stream>>>(logits, d_out + 4*131072);
}